// Round 3
// baseline (2411.240 us; speedup 1.0000x reference)
//
#include <hip/hip_runtime.h>

#define NB   8
#define NPT  2048
#define NF   128
#define CR   64
#define EPSI 1e-5

// ============================ kNN (top-16, 2-D, exact f32+FMA emulation of np/jax) ============================
// Reference: inner = 2*einsum('bcn,bcm->bnm'); xx = sum(x*x,1); dist = xx_q - inner + xx_m.
// numpy einsum (npyv_muladd) and jax dot_general both evaluate the K=2 contraction as
//   fma(s1, v, fl(s0*u))   (first product rounded, second fused)
// while xx is an add-reduce of precomputed squares: fl(fl(x^2)+fl(y^2)).
// We reproduce that rounding exactly; top-k ORDER (which the torch-view scrambles
// are sensitive to) then matches bit-for-bit. Ties: lower index first (lax.top_k stable).
__global__ void __launch_bounds__(256) knn_kernel(const float* __restrict__ xyz,
                                                  int* __restrict__ idx16) {
  __shared__ float px[NPT], py[NPT], sxx[NPT];
  int b = blockIdx.x >> 3;                       // 8 blocks per batch
  int q = ((blockIdx.x & 7) << 8) | threadIdx.x;
  const float* xb = xyz + b * 3 * NPT;
  for (int i = threadIdx.x; i < NPT; i += 256) {
    float x = xb[i], y = xb[NPT + i];
    px[i] = x; py[i] = y;
    sxx[i] = __fadd_rn(__fmul_rn(x, x), __fmul_rn(y, y));   // fl(fl(x^2)+fl(y^2))
  }
  __syncthreads();
  float qx = px[q], qy = py[q];
  float qxx = sxx[q];
  float bd[16]; int bi[16];
#pragma unroll
  for (int j = 0; j < 16; ++j) { bd[j] = 1e38f; bi[j] = 0x7fffffff; }
  for (int m = 0; m < NPT; ++m) {
    float inner_s = __fmaf_rn(qy, py[m], __fmul_rn(qx, px[m]));  // fma(c=1, fl(c=0 product))
    float inner = __fmul_rn(2.0f, inner_s);                      // exact *2
    float d = __fadd_rn(__fsub_rn(qxx, inner), sxx[m]);          // (xx_q - inner) + xx_m
    if (d < bd[15] || (d == bd[15] && m < bi[15])) {
      // branchless sorted insert, all static indices (keeps arrays in VGPRs)
#pragma unroll
      for (int j = 15; j >= 1; --j) {
        bool sj  = (bd[j]   < d) || (bd[j]   == d && bi[j]   < m);
        bool sj1 = (bd[j-1] < d) || (bd[j-1] == d && bi[j-1] < m);
        float nd = sj ? bd[j] : (sj1 ? d : bd[j-1]);
        int   ni = sj ? bi[j] : (sj1 ? m : bi[j-1]);
        bd[j] = nd; bi[j] = ni;
      }
      bool s0 = (bd[0] < d) || (bd[0] == d && bi[0] < m);
      if (!s0) { bd[0] = d; bi[0] = m; }
    }
  }
  int* o = idx16 + ((b * NPT + q) << 4);
#pragma unroll
  for (int j = 0; j < 16; ++j) o[j] = bi[j];
}

// ============================ pointwise conv + f64 channel stats ============================
template<int IC, int OC>
__global__ void __launch_bounds__(256) conv_stats(const float* __restrict__ in,
                                                  const float* __restrict__ w,
                                                  const float* __restrict__ bias,
                                                  float* __restrict__ outp,
                                                  double* __restrict__ stats) {
  // grid: NB * (OC/4) * (NPT/256); block owns 4 output channels x 256 points
  int bz = blockIdx.x;
  int n  = ((bz & 7) << 8) | threadIdx.x;
  int o0 = ((bz >> 3) % (OC / 4)) * 4;
  int b  = bz / (8 * (OC / 4));
  const float* inb = in + b * IC * NPT + n;
  float a0 = bias[o0], a1 = bias[o0 + 1], a2 = bias[o0 + 2], a3 = bias[o0 + 3];
  const float* w0 = w + (o0    ) * IC;
  const float* w1 = w + (o0 + 1) * IC;
  const float* w2 = w + (o0 + 2) * IC;
  const float* w3 = w + (o0 + 3) * IC;
#pragma unroll 8
  for (int f = 0; f < IC; ++f) {
    float v = inb[f * NPT];
    a0 += w0[f] * v; a1 += w1[f] * v; a2 += w2[f] * v; a3 += w3[f] * v;
  }
  float* ob = outp + b * OC * NPT + n;
  ob[(o0    ) * NPT] = a0;
  ob[(o0 + 1) * NPT] = a1;
  ob[(o0 + 2) * NPT] = a2;
  ob[(o0 + 3) * NPT] = a3;
  __shared__ double red[4][4][2];
  float av[4] = {a0, a1, a2, a3};
  int lane = threadIdx.x & 63, wid = threadIdx.x >> 6;
#pragma unroll
  for (int j = 0; j < 4; ++j) {
    double s1 = (double)av[j];
    double s2 = (double)av[j] * (double)av[j];
#pragma unroll
    for (int off = 32; off; off >>= 1) { s1 += __shfl_down(s1, off); s2 += __shfl_down(s2, off); }
    if (lane == 0) { red[wid][j][0] = s1; red[wid][j][1] = s2; }
  }
  __syncthreads();
  if (threadIdx.x < 4) {
    int j = threadIdx.x;
    double S1 = red[0][j][0] + red[1][j][0] + red[2][j][0] + red[3][j][0];
    double S2 = red[0][j][1] + red[1][j][1] + red[2][j][1] + red[3][j][1];
    atomicAdd(&stats[o0 + j], S1);
    atomicAdd(&stats[OC + o0 + j], S2);
  }
}

// ============================ BN finalize + ReLU (+optional residual) ============================
template<int C>
__global__ void __launch_bounds__(256) bn_apply(const float* __restrict__ pre,
                                                const float* __restrict__ addsrc,
                                                float* __restrict__ outp,
                                                const double* __restrict__ stats,
                                                const float* __restrict__ gam,
                                                const float* __restrict__ bet,
                                                double inv_cnt) {
  __shared__ float sc[C], sh[C];
  for (int c = threadIdx.x; c < C; c += 256) {
    double mu    = stats[c] * inv_cnt;
    double var   = stats[C + c] * inv_cnt - mu * mu;
    double scale = (double)gam[c] / sqrt(var + EPSI);
    sc[c] = (float)scale;
    sh[c] = (float)((double)bet[c] - mu * scale);
  }
  __syncthreads();
  int total = NB * C * NPT;
  for (int i = blockIdx.x * 256 + threadIdx.x; i < total; i += gridDim.x * 256) {
    int c = (i >> 11) & (C - 1);                 // i/NPT % C  (NPT=2048, C pow2)
    float v = pre[i] * sc[c] + sh[c];
    v = v > 0.f ? v : 0.f;
    if (addsrc) v += addsrc[i];
    outp[i] = v;
  }
}

// ============================ DSgroupMLP: scrambled gather + 64x64 FC + max over k ============================
__global__ void __launch_bounds__(256) dsgroup_kernel(const float* __restrict__ x1,
                                                      const int* __restrict__ idx16,
                                                      const float* __restrict__ wf,
                                                      const float* __restrict__ bfp,
                                                      float* __restrict__ hmax,
                                                      double* __restrict__ stats) {
  __shared__ float wfT[64 * 65];
  __shared__ double dred[4][64][2];
  for (int i = threadIdx.x; i < 64 * 64; i += 256) {
    int o = i >> 6, f = i & 63;
    wfT[f * 65 + o] = wf[i];                     // i = o*64+f
  }
  __syncthreads();
  int lane = threadIdx.x & 63, wid = threadIdx.x >> 6;
  int wave = blockIdx.x * 4 + wid;               // grid 1024 -> 4096 waves, 4 pts/wave
  float bo = bfp[lane];
  double s1 = 0.0, s2 = 0.0;
  for (int p = 0; p < 4; ++p) {
    int pt = wave * 4 + p;
    int b = pt >> 11, n = pt & 2047;
    int src[8];
#pragma unroll
    for (int k = 0; k < 8; ++k) {
      int j = k * NPT + n;                       // torch-view scramble: idx[(j>>3), j&7]
      src[k] = idx16[((b * NPT + (j >> 3)) << 4) | (j & 7)];
    }
    float acc[8];
#pragma unroll
    for (int k = 0; k < 8; ++k) acc[k] = bo;
    const float* x1b = x1 + b * CR * NPT;
    for (int f = 0; f < 64; ++f) {
      float wv = wfT[f * 65 + lane];             // lane = output channel o
      const float* row = x1b + f * NPT;
#pragma unroll
      for (int k = 0; k < 8; ++k) acc[k] += row[src[k]] * wv;
    }
    float hm = acc[0];
#pragma unroll
    for (int k = 0; k < 8; ++k) {
      hm = fmaxf(hm, acc[k]);
      s1 += (double)acc[k];
      s2 += (double)acc[k] * (double)acc[k];
    }
    hmax[(b * CR + lane) * NPT + n] = hm;        // max commutes with BN+ReLU (gamma>0)
  }
  dred[wid][lane][0] = s1; dred[wid][lane][1] = s2;
  __syncthreads();
  if (threadIdx.x < 64) {
    double S1 = dred[0][threadIdx.x][0] + dred[1][threadIdx.x][0] + dred[2][threadIdx.x][0] + dred[3][threadIdx.x][0];
    double S2 = dred[0][threadIdx.x][1] + dred[1][threadIdx.x][1] + dred[2][threadIdx.x][1] + dred[3][threadIdx.x][1];
    atomicAdd(&stats[threadIdx.x], S1);
    atomicAdd(&stats[64 + threadIdx.x], S2);
  }
}

// ============================ FeatureLaplacian: scrambled mean-gather + 64x64 FC ============================
__global__ void __launch_bounds__(256) lap_kernel(const float* __restrict__ x2,
                                                  const int* __restrict__ idx16,
                                                  const float* __restrict__ wl,
                                                  const float* __restrict__ blp,
                                                  float* __restrict__ tpre,
                                                  double* __restrict__ stats) {
  __shared__ float wlT[64 * 65];
  __shared__ double dred[4][64][2];
  for (int i = threadIdx.x; i < 64 * 64; i += 256) {
    int o = i >> 6, f = i & 63;
    wlT[f * 65 + o] = wl[i];
  }
  __syncthreads();
  int lane = threadIdx.x & 63, wid = threadIdx.x >> 6;
  int wave = blockIdx.x * 4 + wid;
  int g = lane >> 4, cc = lane & 15;             // lane covers (f>>4, f&15) grid for the mean
  float blv = blp[lane];
  double s1 = 0.0, s2 = 0.0;
  for (int p = 0; p < 4; ++p) {
    int pt = wave * 4 + p;
    int b = pt >> 11, n = pt & 2047;
    int ch = n >> 5;                             // gathered CHANNEL is n>>5 (torch-view scramble)
    int r0 = (n & 31) << 6;
    const float* xrow = x2 + (b * CR + ch) * NPT;
    const int* ib = idx16 + ((b * NPT + r0) << 4);
    float msum = 0.f;
#pragma unroll
    for (int kk = 0; kk < 16; ++kk) {
      int sidx = ib[(((kk << 2) + g) << 4) | cc];  // row (n%32)*64 + kk*4 + g, col f&15
      msum += xrow[sidx];
    }
    float mval = msum * 0.0625f;                 // m for channel f sits in lane f
    float acc = blv;
    const float* xcol = x2 + b * CR * NPT + n;
    for (int f = 0; f < 64; ++f) {
      float mf = __shfl(mval, f);
      acc += wlT[f * 65 + lane] * (xcol[f * NPT] - mf);
    }
    tpre[(b * CR + lane) * NPT + n] = acc;
    s1 += (double)acc;
    s2 += (double)acc * (double)acc;
  }
  dred[wid][lane][0] = s1; dred[wid][lane][1] = s2;
  __syncthreads();
  if (threadIdx.x < 64) {
    double S1 = dred[0][threadIdx.x][0] + dred[1][threadIdx.x][0] + dred[2][threadIdx.x][0] + dred[3][threadIdx.x][0];
    double S2 = dred[0][threadIdx.x][1] + dred[1][threadIdx.x][1] + dred[2][threadIdx.x][1] + dred[3][threadIdx.x][1];
    atomicAdd(&stats[threadIdx.x], S1);
    atomicAdd(&stats[64 + threadIdx.x], S2);
  }
}

// ============================ launch ============================
extern "C" void kernel_launch(void* const* d_in, const int* in_sizes, int n_in,
                              void* d_out, int out_size, void* d_ws, size_t ws_size,
                              hipStream_t stream) {
  const float* xyz  = (const float*)d_in[0];
  const float* feat = (const float*)d_in[1];
  const float* w1   = (const float*)d_in[2];
  const float* b1   = (const float*)d_in[3];
  const float* g1   = (const float*)d_in[4];
  const float* be1  = (const float*)d_in[5];
  const float* wf   = (const float*)d_in[6];
  const float* bf   = (const float*)d_in[7];
  const float* gg   = (const float*)d_in[8];
  const float* bg   = (const float*)d_in[9];
  const float* wl   = (const float*)d_in[10];
  const float* bl   = (const float*)d_in[11];
  const float* gl   = (const float*)d_in[12];
  const float* bel  = (const float*)d_in[13];
  const float* w2   = (const float*)d_in[14];
  const float* b2   = (const float*)d_in[15];
  const float* g2   = (const float*)d_in[16];
  const float* be2  = (const float*)d_in[17];
  const float* w3   = (const float*)d_in[18];
  const float* b3   = (const float*)d_in[19];
  const float* g3   = (const float*)d_in[20];
  const float* be3  = (const float*)d_in[21];
  float* out = (float*)d_out;

  // d_out doubles as scratch for buffers dead before mlp3 writes it:
  float* x1   = out;                       // [B][64][N]  4MB   (pre->post BN in place)
  float* tpre = out + 1048576;             // [B][64][N]  4MB
  int*  idx16 = (int*)(out + 2097152);     // [B][N][16]  1MB
  // ws: x2 (hmax -> x2 -> x3 in place), y2, f64 stats
  float*  x2    = (float*)d_ws;            // 4MB
  float*  y2    = x2 + 1048576;            // 8MB
  double* stats = (double*)((char*)d_ws + (12u << 20));
  double* st0 = stats;        // 128 (mlp1)
  double* stg = stats + 128;  // 128 (dsgroup)
  double* stl = stats + 256;  // 128 (laplacian)
  double* st2 = stats + 384;  // 256 (mlp2)
  double* st3 = stats + 640;  // 512 (mlp3)

  hipMemsetAsync(stats, 0, 1152 * sizeof(double), stream);

  knn_kernel<<<NB * 8, 256, 0, stream>>>(xyz, idx16);

  // mlp1: feat[128] -> x1[64] + stats
  conv_stats<128, 64><<<NB * 16 * 8, 256, 0, stream>>>(feat, w1, b1, x1, st0);
  bn_apply<64><<<1024, 256, 0, stream>>>(x1, nullptr, x1, st0, g1, be1, 1.0 / 16384.0);

  // DSgroupMLP
  dsgroup_kernel<<<1024, 256, 0, stream>>>(x1, idx16, wf, bf, x2, stg);
  bn_apply<64><<<1024, 256, 0, stream>>>(x2, nullptr, x2, stg, gg, bg, 1.0 / 131072.0);

  // FeatureLaplacian: tpre, then x3 = x2 + relu(BN(tpre)) in place over x2
  lap_kernel<<<1024, 256, 0, stream>>>(x2, idx16, wl, bl, tpre, stl);
  bn_apply<64><<<1024, 256, 0, stream>>>(tpre, x2, x2, stl, gl, bel, 1.0 / 16384.0);

  // mlp2: x3[64] -> y2[128]; y2 = relu(BN) + feat
  conv_stats<64, 128><<<NB * 32 * 8, 256, 0, stream>>>(x2, w2, b2, y2, st2);
  bn_apply<128><<<1024, 256, 0, stream>>>(y2, feat, y2, st2, g2, be2, 1.0 / 16384.0);

  // mlp3: y2[128] -> out[256]; out = relu(BN) in place
  conv_stats<128, 256><<<NB * 64 * 8, 256, 0, stream>>>(y2, w3, b3, out, st3);
  bn_apply<256><<<1024, 256, 0, stream>>>(out, nullptr, out, st3, g3, be3, 1.0 / 16384.0);
}

// Round 6
// 343.014 us; speedup vs baseline: 7.0296x; 7.0296x over previous
//
#include <hip/hip_runtime.h>

#define NB   8
#define NPT  2048
#define NF   128
#define CR   64
#define EPSI 1e-5

// ============================ kNN (top-16, 2-D, exact f32+FMA emulation of np/jax) ============================
// Distance rounding verified bit-exact vs the np reference in round 3 (passed):
//   inner_s = fma(qy, py, fl(qx*px)); d = fl(fl(qxx - fl(2*inner_s)) + xx_m)
//   xx = fl(fl(x^2)+fl(y^2)); ties -> lower index (stable top_k).
// ONE WAVE PER QUERY, mask-based repeated extract-min (no sorted-list chains):
// each lane holds 32 candidate distances in VGPRs (candidate m = lane + 64*j);
// 16 rounds of { per-lane min-scan -> 6-step shfl_xor butterfly on (d, idx) ->
// winner parked in lane r -> owner masks its slot to +inf }. Repeated global
// extract-min under lexicographic (d, idx) == stable top-16, independent of
// the candidate partition. All register indices static -> VGPR-resident.
__global__ void __launch_bounds__(256) knn_kernel(const float* __restrict__ xyz,
                                                  int* __restrict__ idx16) {
  __shared__ float px[NPT], py[NPT], sxx[NPT];
  // 4096 blocks: 512 blocks/batch, 4 queries/block (one per wave)
  int b = blockIdx.x >> 9;
  const float* xb = xyz + b * 3 * NPT;
  for (int i = threadIdx.x; i < NPT; i += 256) {
    float x = xb[i], y = xb[NPT + i];
    px[i] = x; py[i] = y;
    sxx[i] = __fadd_rn(__fmul_rn(x, x), __fmul_rn(y, y));
  }
  __syncthreads();
  int lane = threadIdx.x & 63, wid = threadIdx.x >> 6;
  int q = ((blockIdx.x & 511) << 2) | wid;
  float qx = px[q], qy = py[q], qxx = sxx[q];
  float dc[32];
#pragma unroll 4
  for (int j = 0; j < 32; ++j) {
    int m = lane + (j << 6);                     // stride-1 across lanes: 2-way LDS alias (free)
    float inner_s = __fmaf_rn(qy, py[m], __fmul_rn(qx, px[m]));
    dc[j] = __fadd_rn(__fsub_rn(qxx, __fmul_rn(2.0f, inner_s)), sxx[m]);
  }
  int keep = 0;
  for (int r = 0; r < 16; ++r) {
    // per-lane min over 32 slots, tie -> smaller j (== smaller global m for fixed lane)
    float dmin = dc[0]; int jmin = 0;
#pragma unroll
    for (int j = 1; j < 32; ++j) {
      bool better = dc[j] < dmin;                // strict: ties keep smaller j
      dmin = better ? dc[j] : dmin;
      jmin = better ? j : jmin;
    }
    float hd = dmin;
    int   hm = lane + (jmin << 6);               // global candidate index
    // butterfly: global min under (d, idx)
#pragma unroll
    for (int off = 1; off < 64; off <<= 1) {
      float od = __shfl_xor(hd, off);
      int   om = __shfl_xor(hm, off);
      bool take = (od < hd) || (od == hd && om < hm);
      hd = take ? od : hd;
      hm = take ? om : hm;
    }
    if (lane == r) keep = hm;                    // result r parked in lane r
    // owner lane masks its winning slot (static-index selects, stays in VGPRs)
    bool own = (hm & 63) == lane;
    int jw = hm >> 6;
#pragma unroll
    for (int j = 0; j < 32; ++j)
      dc[j] = (own && j == jw) ? 1e38f : dc[j];
  }
  if (lane < 16) idx16[((b * NPT + q) << 4) + lane] = keep;
}

// ============================ pointwise conv + f64 channel stats ============================
template<int IC, int OC>
__global__ void __launch_bounds__(256) conv_stats(const float* __restrict__ in,
                                                  const float* __restrict__ w,
                                                  const float* __restrict__ bias,
                                                  float* __restrict__ outp,
                                                  double* __restrict__ stats) {
  // grid: NB * (OC/4) * (NPT/256); block owns 4 output channels x 256 points
  int bz = blockIdx.x;
  int n  = ((bz & 7) << 8) | threadIdx.x;
  int o0 = ((bz >> 3) % (OC / 4)) * 4;
  int b  = bz / (8 * (OC / 4));
  const float* inb = in + b * IC * NPT + n;
  float a0 = bias[o0], a1 = bias[o0 + 1], a2 = bias[o0 + 2], a3 = bias[o0 + 3];
  const float* w0 = w + (o0    ) * IC;
  const float* w1 = w + (o0 + 1) * IC;
  const float* w2 = w + (o0 + 2) * IC;
  const float* w3 = w + (o0 + 3) * IC;
#pragma unroll 8
  for (int f = 0; f < IC; ++f) {
    float v = inb[f * NPT];
    a0 += w0[f] * v; a1 += w1[f] * v; a2 += w2[f] * v; a3 += w3[f] * v;
  }
  float* ob = outp + b * OC * NPT + n;
  ob[(o0    ) * NPT] = a0;
  ob[(o0 + 1) * NPT] = a1;
  ob[(o0 + 2) * NPT] = a2;
  ob[(o0 + 3) * NPT] = a3;
  __shared__ double red[4][4][2];
  float av[4] = {a0, a1, a2, a3};
  int lane = threadIdx.x & 63, wid = threadIdx.x >> 6;
#pragma unroll
  for (int j = 0; j < 4; ++j) {
    double s1 = (double)av[j];
    double s2 = (double)av[j] * (double)av[j];
#pragma unroll
    for (int off = 32; off; off >>= 1) { s1 += __shfl_down(s1, off); s2 += __shfl_down(s2, off); }
    if (lane == 0) { red[wid][j][0] = s1; red[wid][j][1] = s2; }
  }
  __syncthreads();
  if (threadIdx.x < 4) {
    int j = threadIdx.x;
    double S1 = red[0][j][0] + red[1][j][0] + red[2][j][0] + red[3][j][0];
    double S2 = red[0][j][1] + red[1][j][1] + red[2][j][1] + red[3][j][1];
    atomicAdd(&stats[o0 + j], S1);
    atomicAdd(&stats[OC + o0 + j], S2);
  }
}

// ============================ BN finalize + ReLU (+optional residual) ============================
template<int C>
__global__ void __launch_bounds__(256) bn_apply(const float* __restrict__ pre,
                                                const float* __restrict__ addsrc,
                                                float* __restrict__ outp,
                                                const double* __restrict__ stats,
                                                const float* __restrict__ gam,
                                                const float* __restrict__ bet,
                                                double inv_cnt) {
  __shared__ float sc[C], sh[C];
  for (int c = threadIdx.x; c < C; c += 256) {
    double mu    = stats[c] * inv_cnt;
    double var   = stats[C + c] * inv_cnt - mu * mu;
    double scale = (double)gam[c] / sqrt(var + EPSI);
    sc[c] = (float)scale;
    sh[c] = (float)((double)bet[c] - mu * scale);
  }
  __syncthreads();
  int total = NB * C * NPT;
  for (int i = blockIdx.x * 256 + threadIdx.x; i < total; i += gridDim.x * 256) {
    int c = (i >> 11) & (C - 1);                 // i/NPT % C  (NPT=2048, C pow2)
    float v = pre[i] * sc[c] + sh[c];
    v = v > 0.f ? v : 0.f;
    if (addsrc) v += addsrc[i];
    outp[i] = v;
  }
}

// ============================ DSgroupMLP: scrambled gather + 64x64 FC + max over k ============================
__global__ void __launch_bounds__(256) dsgroup_kernel(const float* __restrict__ x1,
                                                      const int* __restrict__ idx16,
                                                      const float* __restrict__ wf,
                                                      const float* __restrict__ bfp,
                                                      float* __restrict__ hmax,
                                                      double* __restrict__ stats) {
  __shared__ float wfT[64 * 65];
  __shared__ double dred[4][64][2];
  for (int i = threadIdx.x; i < 64 * 64; i += 256) {
    int o = i >> 6, f = i & 63;
    wfT[f * 65 + o] = wf[i];                     // i = o*64+f
  }
  __syncthreads();
  int lane = threadIdx.x & 63, wid = threadIdx.x >> 6;
  int wave = blockIdx.x * 4 + wid;               // grid 1024 -> 4096 waves, 4 pts/wave
  float bo = bfp[lane];
  double s1 = 0.0, s2 = 0.0;
  for (int p = 0; p < 4; ++p) {
    int pt = wave * 4 + p;
    int b = pt >> 11, n = pt & 2047;
    int src[8];
#pragma unroll
    for (int k = 0; k < 8; ++k) {
      int j = k * NPT + n;                       // torch-view scramble: idx[(j>>3), j&7]
      src[k] = idx16[((b * NPT + (j >> 3)) << 4) | (j & 7)];
    }
    float acc[8];
#pragma unroll
    for (int k = 0; k < 8; ++k) acc[k] = bo;
    const float* x1b = x1 + b * CR * NPT;
    for (int f = 0; f < 64; ++f) {
      float wv = wfT[f * 65 + lane];             // lane = output channel o
      const float* row = x1b + f * NPT;
#pragma unroll
      for (int k = 0; k < 8; ++k) acc[k] += row[src[k]] * wv;
    }
    float hm = acc[0];
#pragma unroll
    for (int k = 0; k < 8; ++k) {
      hm = fmaxf(hm, acc[k]);
      s1 += (double)acc[k];
      s2 += (double)acc[k] * (double)acc[k];
    }
    hmax[(b * CR + lane) * NPT + n] = hm;        // max commutes with BN+ReLU (gamma>0)
  }
  dred[wid][lane][0] = s1; dred[wid][lane][1] = s2;
  __syncthreads();
  if (threadIdx.x < 64) {
    double S1 = dred[0][threadIdx.x][0] + dred[1][threadIdx.x][0] + dred[2][threadIdx.x][0] + dred[3][threadIdx.x][0];
    double S2 = dred[0][threadIdx.x][1] + dred[1][threadIdx.x][1] + dred[2][threadIdx.x][1] + dred[3][threadIdx.x][1];
    atomicAdd(&stats[threadIdx.x], S1);
    atomicAdd(&stats[64 + threadIdx.x], S2);
  }
}

// ============================ FeatureLaplacian: scrambled mean-gather + 64x64 FC ============================
__global__ void __launch_bounds__(256) lap_kernel(const float* __restrict__ x2,
                                                  const int* __restrict__ idx16,
                                                  const float* __restrict__ wl,
                                                  const float* __restrict__ blp,
                                                  float* __restrict__ tpre,
                                                  double* __restrict__ stats) {
  __shared__ float wlT[64 * 65];
  __shared__ double dred[4][64][2];
  for (int i = threadIdx.x; i < 64 * 64; i += 256) {
    int o = i >> 6, f = i & 63;
    wlT[f * 65 + o] = wl[i];
  }
  __syncthreads();
  int lane = threadIdx.x & 63, wid = threadIdx.x >> 6;
  int wave = blockIdx.x * 4 + wid;
  int g = lane >> 4, cc = lane & 15;             // lane covers (f>>4, f&15) grid for the mean
  float blv = blp[lane];
  double s1 = 0.0, s2 = 0.0;
  for (int p = 0; p < 4; ++p) {
    int pt = wave * 4 + p;
    int b = pt >> 11, n = pt & 2047;
    int ch = n >> 5;                             // gathered CHANNEL is n>>5 (torch-view scramble)
    int r0 = (n & 31) << 6;
    const float* xrow = x2 + (b * CR + ch) * NPT;
    const int* ib = idx16 + ((b * NPT + r0) << 4);
    float msum = 0.f;
#pragma unroll
    for (int kk = 0; kk < 16; ++kk) {
      int sidx = ib[(((kk << 2) + g) << 4) | cc];  // row (n%32)*64 + kk*4 + g, col f&15
      msum += xrow[sidx];
    }
    float mval = msum * 0.0625f;                 // m for channel f sits in lane f
    float acc = blv;
    const float* xcol = x2 + b * CR * NPT + n;
    for (int f = 0; f < 64; ++f) {
      float mf = __shfl(mval, f);
      acc += wlT[f * 65 + lane] * (xcol[f * NPT] - mf);
    }
    tpre[(b * CR + lane) * NPT + n] = acc;
    s1 += (double)acc;
    s2 += (double)acc * (double)acc;
  }
  dred[wid][lane][0] = s1; dred[wid][lane][1] = s2;
  __syncthreads();
  if (threadIdx.x < 64) {
    double S1 = dred[0][threadIdx.x][0] + dred[1][threadIdx.x][0] + dred[2][threadIdx.x][0] + dred[3][threadIdx.x][0];
    double S2 = dred[0][threadIdx.x][1] + dred[1][threadIdx.x][1] + dred[2][threadIdx.x][1] + dred[3][threadIdx.x][1];
    atomicAdd(&stats[threadIdx.x], S1);
    atomicAdd(&stats[64 + threadIdx.x], S2);
  }
}

// ============================ launch ============================
extern "C" void kernel_launch(void* const* d_in, const int* in_sizes, int n_in,
                              void* d_out, int out_size, void* d_ws, size_t ws_size,
                              hipStream_t stream) {
  const float* xyz  = (const float*)d_in[0];
  const float* feat = (const float*)d_in[1];
  const float* w1   = (const float*)d_in[2];
  const float* b1   = (const float*)d_in[3];
  const float* g1   = (const float*)d_in[4];
  const float* be1  = (const float*)d_in[5];
  const float* wf   = (const float*)d_in[6];
  const float* bf   = (const float*)d_in[7];
  const float* gg   = (const float*)d_in[8];
  const float* bg   = (const float*)d_in[9];
  const float* wl   = (const float*)d_in[10];
  const float* bl   = (const float*)d_in[11];
  const float* gl   = (const float*)d_in[12];
  const float* bel  = (const float*)d_in[13];
  const float* w2   = (const float*)d_in[14];
  const float* b2   = (const float*)d_in[15];
  const float* g2   = (const float*)d_in[16];
  const float* be2  = (const float*)d_in[17];
  const float* w3   = (const float*)d_in[18];
  const float* b3   = (const float*)d_in[19];
  const float* g3   = (const float*)d_in[20];
  const float* be3  = (const float*)d_in[21];
  float* out = (float*)d_out;

  // d_out doubles as scratch for buffers dead before mlp3 writes it:
  float* x1   = out;                       // [B][64][N]  4MB   (pre->post BN in place)
  float* tpre = out + 1048576;             // [B][64][N]  4MB
  int*  idx16 = (int*)(out + 2097152);     // [B][N][16]  1MB
  // ws: x2 (hmax -> x2 -> x3 in place), y2, f64 stats
  float*  x2    = (float*)d_ws;            // 4MB
  float*  y2    = x2 + 1048576;            // 8MB
  double* stats = (double*)((char*)d_ws + (12u << 20));
  double* st0 = stats;        // 128 (mlp1)
  double* stg = stats + 128;  // 128 (dsgroup)
  double* stl = stats + 256;  // 128 (laplacian)
  double* st2 = stats + 384;  // 256 (mlp2)
  double* st3 = stats + 640;  // 512 (mlp3)

  hipMemsetAsync(stats, 0, 1152 * sizeof(double), stream);

  knn_kernel<<<4096, 256, 0, stream>>>(xyz, idx16);

  // mlp1: feat[128] -> x1[64] + stats
  conv_stats<128, 64><<<NB * 16 * 8, 256, 0, stream>>>(feat, w1, b1, x1, st0);
  bn_apply<64><<<1024, 256, 0, stream>>>(x1, nullptr, x1, st0, g1, be1, 1.0 / 16384.0);

  // DSgroupMLP
  dsgroup_kernel<<<1024, 256, 0, stream>>>(x1, idx16, wf, bf, x2, stg);
  bn_apply<64><<<1024, 256, 0, stream>>>(x2, nullptr, x2, stg, gg, bg, 1.0 / 131072.0);

  // FeatureLaplacian: tpre, then x3 = x2 + relu(BN(tpre)) in place over x2
  lap_kernel<<<1024, 256, 0, stream>>>(x2, idx16, wl, bl, tpre, stl);
  bn_apply<64><<<1024, 256, 0, stream>>>(tpre, x2, x2, stl, gl, bel, 1.0 / 16384.0);

  // mlp2: x3[64] -> y2[128]; y2 = relu(BN) + feat
  conv_stats<64, 128><<<NB * 32 * 8, 256, 0, stream>>>(x2, w2, b2, y2, st2);
  bn_apply<128><<<1024, 256, 0, stream>>>(y2, feat, y2, st2, g2, be2, 1.0 / 16384.0);

  // mlp3: y2[128] -> out[256]; out = relu(BN) in place
  conv_stats<128, 256><<<NB * 64 * 8, 256, 0, stream>>>(y2, w3, b3, out, st3);
  bn_apply<256><<<1024, 256, 0, stream>>>(out, nullptr, out, st3, g3, be3, 1.0 / 16384.0);
}

// Round 7
// 302.305 us; speedup vs baseline: 7.9762x; 1.1347x over previous
//
#include <hip/hip_runtime.h>

#define NB   8
#define NPT  2048
#define NF   128
#define CR   64
#define EPSI 1e-5

// ============================ kNN (top-16, 2-D, exact f32+FMA emulation of np/jax) ============================
// PROVEN (round 6): passes, 105 us. Distance rounding bit-exact vs np reference;
// mask-based repeated extract-min, lexicographic (d, idx) everywhere. FROZEN.
__global__ void __launch_bounds__(256) knn_kernel(const float* __restrict__ xyz,
                                                  int* __restrict__ idx16) {
  __shared__ float px[NPT], py[NPT], sxx[NPT];
  int b = blockIdx.x >> 9;
  const float* xb = xyz + b * 3 * NPT;
  for (int i = threadIdx.x; i < NPT; i += 256) {
    float x = xb[i], y = xb[NPT + i];
    px[i] = x; py[i] = y;
    sxx[i] = __fadd_rn(__fmul_rn(x, x), __fmul_rn(y, y));
  }
  __syncthreads();
  int lane = threadIdx.x & 63, wid = threadIdx.x >> 6;
  int q = ((blockIdx.x & 511) << 2) | wid;
  float qx = px[q], qy = py[q], qxx = sxx[q];
  float dc[32];
#pragma unroll 4
  for (int j = 0; j < 32; ++j) {
    int m = lane + (j << 6);
    float inner_s = __fmaf_rn(qy, py[m], __fmul_rn(qx, px[m]));
    dc[j] = __fadd_rn(__fsub_rn(qxx, __fmul_rn(2.0f, inner_s)), sxx[m]);
  }
  int keep = 0;
  for (int r = 0; r < 16; ++r) {
    float dmin = dc[0]; int jmin = 0;
#pragma unroll
    for (int j = 1; j < 32; ++j) {
      bool better = dc[j] < dmin;
      dmin = better ? dc[j] : dmin;
      jmin = better ? j : jmin;
    }
    float hd = dmin;
    int   hm = lane + (jmin << 6);
#pragma unroll
    for (int off = 1; off < 64; off <<= 1) {
      float od = __shfl_xor(hd, off);
      int   om = __shfl_xor(hm, off);
      bool take = (od < hd) || (od == hd && om < hm);
      hd = take ? od : hd;
      hm = take ? om : hm;
    }
    if (lane == r) keep = hm;
    bool own = (hm & 63) == lane;
    int jw = hm >> 6;
#pragma unroll
    for (int j = 0; j < 32; ++j)
      dc[j] = (own && j == jw) ? 1e38f : dc[j];
  }
  if (lane < 16) idx16[((b * NPT + q) << 4) + lane] = keep;
}

// ============================ pointwise conv + f64 channel stats (8 channels/block) ============================
template<int IC, int OC>
__global__ void __launch_bounds__(256) conv_stats(const float* __restrict__ in,
                                                  const float* __restrict__ w,
                                                  const float* __restrict__ bias,
                                                  float* __restrict__ outp,
                                                  double* __restrict__ stats) {
  // grid: NB * (OC/8) * 8; block owns 8 output channels x 256 points
  int bz = blockIdx.x;
  int n  = ((bz & 7) << 8) | threadIdx.x;
  int o0 = ((bz >> 3) % (OC / 8)) * 8;
  int b  = bz / (8 * (OC / 8));
  const float* inb = in + b * IC * NPT + n;
  float a[8];
#pragma unroll
  for (int t = 0; t < 8; ++t) a[t] = bias[o0 + t];
  const float* wb = w + o0 * IC;
#pragma unroll 4
  for (int f = 0; f < IC; ++f) {
    float v = inb[f * NPT];
#pragma unroll
    for (int t = 0; t < 8; ++t) a[t] += wb[t * IC + f] * v;   // weights wave-uniform -> scalar pipe
  }
  float* ob = outp + b * OC * NPT + n;
#pragma unroll
  for (int t = 0; t < 8; ++t) ob[(o0 + t) * NPT] = a[t];
  __shared__ double red[4][8][2];
  int lane = threadIdx.x & 63, wid = threadIdx.x >> 6;
#pragma unroll
  for (int j = 0; j < 8; ++j) {
    double s1 = (double)a[j];
    double s2 = (double)a[j] * (double)a[j];
#pragma unroll
    for (int off = 32; off; off >>= 1) { s1 += __shfl_down(s1, off); s2 += __shfl_down(s2, off); }
    if (lane == 0) { red[wid][j][0] = s1; red[wid][j][1] = s2; }
  }
  __syncthreads();
  if (threadIdx.x < 8) {
    int j = threadIdx.x;
    double S1 = red[0][j][0] + red[1][j][0] + red[2][j][0] + red[3][j][0];
    double S2 = red[0][j][1] + red[1][j][1] + red[2][j][1] + red[3][j][1];
    atomicAdd(&stats[o0 + j], S1);
    atomicAdd(&stats[OC + o0 + j], S2);
  }
}

// ============================ BN finalize + ReLU (+optional residual), float4 ============================
template<int C>
__global__ void __launch_bounds__(256) bn_apply(const float* __restrict__ pre,
                                                const float* __restrict__ addsrc,
                                                float* __restrict__ outp,
                                                const double* __restrict__ stats,
                                                const float* __restrict__ gam,
                                                const float* __restrict__ bet,
                                                double inv_cnt) {
  __shared__ float sc[C], sh[C];
  for (int c = threadIdx.x; c < C; c += 256) {
    double mu    = stats[c] * inv_cnt;
    double var   = stats[C + c] * inv_cnt - mu * mu;
    double scale = (double)gam[c] / sqrt(var + EPSI);
    sc[c] = (float)scale;
    sh[c] = (float)((double)bet[c] - mu * scale);
  }
  __syncthreads();
  const float4* pre4 = (const float4*)pre;
  const float4* add4 = (const float4*)addsrc;
  float4* out4 = (float4*)outp;
  int total4 = NB * C * (NPT / 4);
  for (int i = blockIdx.x * 256 + threadIdx.x; i < total4; i += gridDim.x * 256) {
    int c = (i >> 9) & (C - 1);                  // 512 float4 per channel row
    float s = sc[c], h = sh[c];
    float4 v = pre4[i];
    v.x = fmaxf(v.x * s + h, 0.f);
    v.y = fmaxf(v.y * s + h, 0.f);
    v.z = fmaxf(v.z * s + h, 0.f);
    v.w = fmaxf(v.w * s + h, 0.f);
    if (addsrc) {
      float4 a = add4[i];
      v.x += a.x; v.y += a.y; v.z += a.z; v.w += a.w;
    }
    out4[i] = v;
  }
}

// ============================ DSgroupMLP: scrambled gather + 64x64 FC + max over k ============================
__global__ void __launch_bounds__(256) dsgroup_kernel(const float* __restrict__ x1,
                                                      const int* __restrict__ idx16,
                                                      const float* __restrict__ wf,
                                                      const float* __restrict__ bfp,
                                                      float* __restrict__ hmax,
                                                      double* __restrict__ stats) {
  __shared__ float wfT[64 * 65];
  __shared__ double dred[4][64][2];
  for (int i = threadIdx.x; i < 64 * 64; i += 256) {
    int o = i >> 6, f = i & 63;
    wfT[f * 65 + o] = wf[i];                     // i = o*64+f
  }
  __syncthreads();
  int lane = threadIdx.x & 63, wid = threadIdx.x >> 6;
  int wave = blockIdx.x * 4 + wid;               // grid 1024 -> 4096 waves, 4 pts/wave
  float bo = bfp[lane];
  double s1 = 0.0, s2 = 0.0;
  for (int p = 0; p < 4; ++p) {
    int pt = wave * 4 + p;
    int b = pt >> 11, n = pt & 2047;
    int src[8];
#pragma unroll
    for (int k = 0; k < 8; ++k) {
      int j = k * NPT + n;                       // torch-view scramble: idx[(j>>3), j&7]
      src[k] = idx16[((b * NPT + (j >> 3)) << 4) | (j & 7)];
    }
    float acc[8];
#pragma unroll
    for (int k = 0; k < 8; ++k) acc[k] = bo;
    const float* x1b = x1 + b * CR * NPT;
    for (int f = 0; f < 64; ++f) {
      float wv = wfT[f * 65 + lane];             // lane = output channel o
      const float* row = x1b + f * NPT;
#pragma unroll
      for (int k = 0; k < 8; ++k) acc[k] += row[src[k]] * wv;
    }
    float hm = acc[0];
#pragma unroll
    for (int k = 0; k < 8; ++k) {
      hm = fmaxf(hm, acc[k]);
      s1 += (double)acc[k];
      s2 += (double)acc[k] * (double)acc[k];
    }
    hmax[(b * CR + lane) * NPT + n] = hm;        // max commutes with BN+ReLU (gamma>0)
  }
  dred[wid][lane][0] = s1; dred[wid][lane][1] = s2;
  __syncthreads();
  if (threadIdx.x < 64) {
    double S1 = dred[0][threadIdx.x][0] + dred[1][threadIdx.x][0] + dred[2][threadIdx.x][0] + dred[3][threadIdx.x][0];
    double S2 = dred[0][threadIdx.x][1] + dred[1][threadIdx.x][1] + dred[2][threadIdx.x][1] + dred[3][threadIdx.x][1];
    atomicAdd(&stats[threadIdx.x], S1);
    atomicAdd(&stats[64 + threadIdx.x], S2);
  }
}

// ============================ FeatureLaplacian: scrambled mean-gather + 64x64 FC ============================
__global__ void __launch_bounds__(256) lap_kernel(const float* __restrict__ x2,
                                                  const int* __restrict__ idx16,
                                                  const float* __restrict__ wl,
                                                  const float* __restrict__ blp,
                                                  float* __restrict__ tpre,
                                                  double* __restrict__ stats) {
  __shared__ float wlT[64 * 65];
  __shared__ double dred[4][64][2];
  __shared__ float vstage[4][64];                // per-wave (x2[f][n] - mval[f]) staged by lane=f
  for (int i = threadIdx.x; i < 64 * 64; i += 256) {
    int o = i >> 6, f = i & 63;
    wlT[f * 65 + o] = wl[i];
  }
  __syncthreads();
  int lane = threadIdx.x & 63, wid = threadIdx.x >> 6;
  int wave = blockIdx.x * 4 + wid;
  int g = lane >> 4, cc = lane & 15;             // lane covers (f>>4, f&15) grid for the mean
  float blv = blp[lane];
  double s1 = 0.0, s2 = 0.0;
  for (int p = 0; p < 4; ++p) {
    int pt = wave * 4 + p;
    int b = pt >> 11, n = pt & 2047;
    int ch = n >> 5;                             // gathered CHANNEL is n>>5 (torch-view scramble)
    int r0 = (n & 31) << 6;
    const float* xrow = x2 + (b * CR + ch) * NPT;
    const int* ib = idx16 + ((b * NPT + r0) << 4);
    float msum = 0.f;
#pragma unroll
    for (int kk = 0; kk < 16; ++kk) {
      int sidx = ib[(((kk << 2) + g) << 4) | cc];  // row (n%32)*64 + kk*4 + g, col f&15
      msum += xrow[sidx];
    }
    float mval = msum * 0.0625f;                 // m for channel f sits in lane f
    // per-lane column gather: x2[b][f=lane][n]; stage (x - m) for broadcast reads
    float xv = x2[(b * CR + lane) * NPT + n];
    vstage[wid][lane] = xv - mval;               // wave-local; lgkmcnt ordering suffices
    float acc = blv;
    for (int f = 0; f < 64; ++f)
      acc += wlT[f * 65 + lane] * vstage[wid][f];
    tpre[(b * CR + lane) * NPT + n] = acc;
    s1 += (double)acc;
    s2 += (double)acc * (double)acc;
  }
  dred[wid][lane][0] = s1; dred[wid][lane][1] = s2;
  __syncthreads();
  if (threadIdx.x < 64) {
    double S1 = dred[0][threadIdx.x][0] + dred[1][threadIdx.x][0] + dred[2][threadIdx.x][0] + dred[3][threadIdx.x][0];
    double S2 = dred[0][threadIdx.x][1] + dred[1][threadIdx.x][1] + dred[2][threadIdx.x][1] + dred[3][threadIdx.x][1];
    atomicAdd(&stats[threadIdx.x], S1);
    atomicAdd(&stats[64 + threadIdx.x], S2);
  }
}

// ============================ launch ============================
extern "C" void kernel_launch(void* const* d_in, const int* in_sizes, int n_in,
                              void* d_out, int out_size, void* d_ws, size_t ws_size,
                              hipStream_t stream) {
  const float* xyz  = (const float*)d_in[0];
  const float* feat = (const float*)d_in[1];
  const float* w1   = (const float*)d_in[2];
  const float* b1   = (const float*)d_in[3];
  const float* g1   = (const float*)d_in[4];
  const float* be1  = (const float*)d_in[5];
  const float* wf   = (const float*)d_in[6];
  const float* bf   = (const float*)d_in[7];
  const float* gg   = (const float*)d_in[8];
  const float* bg   = (const float*)d_in[9];
  const float* wl   = (const float*)d_in[10];
  const float* bl   = (const float*)d_in[11];
  const float* gl   = (const float*)d_in[12];
  const float* bel  = (const float*)d_in[13];
  const float* w2   = (const float*)d_in[14];
  const float* b2   = (const float*)d_in[15];
  const float* g2   = (const float*)d_in[16];
  const float* be2  = (const float*)d_in[17];
  const float* w3   = (const float*)d_in[18];
  const float* b3   = (const float*)d_in[19];
  const float* g3   = (const float*)d_in[20];
  const float* be3  = (const float*)d_in[21];
  float* out = (float*)d_out;

  // d_out doubles as scratch for buffers dead before mlp3 writes it:
  float* x1   = out;                       // [B][64][N]  4MB   (pre->post BN in place)
  float* tpre = out + 1048576;             // [B][64][N]  4MB
  int*  idx16 = (int*)(out + 2097152);     // [B][N][16]  1MB
  // ws: x2 (hmax -> x2 -> x3 in place), y2, f64 stats
  float*  x2    = (float*)d_ws;            // 4MB
  float*  y2    = x2 + 1048576;            // 8MB
  double* stats = (double*)((char*)d_ws + (12u << 20));
  double* st0 = stats;        // 128 (mlp1)
  double* stg = stats + 128;  // 128 (dsgroup)
  double* stl = stats + 256;  // 128 (laplacian)
  double* st2 = stats + 384;  // 256 (mlp2)
  double* st3 = stats + 640;  // 512 (mlp3)

  hipMemsetAsync(stats, 0, 1152 * sizeof(double), stream);

  knn_kernel<<<4096, 256, 0, stream>>>(xyz, idx16);

  // mlp1: feat[128] -> x1[64] + stats
  conv_stats<128, 64><<<NB * 8 * 8, 256, 0, stream>>>(feat, w1, b1, x1, st0);
  bn_apply<64><<<1024, 256, 0, stream>>>(x1, nullptr, x1, st0, g1, be1, 1.0 / 16384.0);

  // DSgroupMLP
  dsgroup_kernel<<<1024, 256, 0, stream>>>(x1, idx16, wf, bf, x2, stg);
  bn_apply<64><<<1024, 256, 0, stream>>>(x2, nullptr, x2, stg, gg, bg, 1.0 / 131072.0);

  // FeatureLaplacian: tpre, then x3 = x2 + relu(BN(tpre)) in place over x2
  lap_kernel<<<1024, 256, 0, stream>>>(x2, idx16, wl, bl, tpre, stl);
  bn_apply<64><<<1024, 256, 0, stream>>>(tpre, x2, x2, stl, gl, bel, 1.0 / 16384.0);

  // mlp2: x3[64] -> y2[128]; y2 = relu(BN) + feat
  conv_stats<64, 128><<<NB * 16 * 8, 256, 0, stream>>>(x2, w2, b2, y2, st2);
  bn_apply<128><<<1024, 256, 0, stream>>>(y2, feat, y2, st2, g2, be2, 1.0 / 16384.0);

  // mlp3: y2[128] -> out[256]; out = relu(BN) in place
  conv_stats<128, 256><<<NB * 32 * 8, 256, 0, stream>>>(y2, w3, b3, out, st3);
  bn_apply<256><<<1024, 256, 0, stream>>>(out, nullptr, out, st3, g3, be3, 1.0 / 16384.0);
}